// Round 3
// baseline (4908.712 us; speedup 1.0000x reference)
//
#include <hip/hip_runtime.h>
#include <math.h>

// Problem constants (z: [2,16384,256] f32, emb: [8192,256] f32)
#define D_DIM 256
#define NE    8192
#define M_TOT 32768L

// Output layout (f32 elements): z_q_st | loss | idx | age | usage
#define O_LOSS  8388608L
#define O_IDX   8388609L
#define O_AGE   8421377L
#define O_USAGE 8429569L

// ws layout: zzf[32768] f32 | enf[8192] f32

// ---------------------------------------------------------------------------
// Kernel 1: f32 row norms (f64-accumulated, f32-rounded) for z and emb,
// init age/usage defaults, zero loss.
__global__ __launch_bounds__(256) void vq_prep(
    const float* __restrict__ z, const float* __restrict__ emb,
    const float* __restrict__ code_age, const float* __restrict__ code_usage,
    float* __restrict__ out, float* __restrict__ zzf, float* __restrict__ enf) {
  int t = blockIdx.x * 256 + threadIdx.x;  // 0..32767
  {
    const float4* row = reinterpret_cast<const float4*>(z + (size_t)t * D_DIM);
    double s = 0.0;
#pragma unroll
    for (int q = 0; q < D_DIM / 4; ++q) {
      float4 v = row[q];
      s = fma((double)v.x, (double)v.x, s);
      s = fma((double)v.y, (double)v.y, s);
      s = fma((double)v.z, (double)v.z, s);
      s = fma((double)v.w, (double)v.w, s);
    }
    zzf[t] = (float)s;
  }
  if (t < NE) {
    const float4* row = reinterpret_cast<const float4*>(emb + (size_t)t * D_DIM);
    double s = 0.0;
#pragma unroll
    for (int q = 0; q < D_DIM / 4; ++q) {
      float4 v = row[q];
      s = fma((double)v.x, (double)v.x, s);
      s = fma((double)v.y, (double)v.y, s);
      s = fma((double)v.z, (double)v.z, s);
      s = fma((double)v.w, (double)v.w, s);
    }
    enf[t] = (float)s;
    out[O_AGE + t] = code_age[t] + 1.0f;
    out[O_USAGE + t] = code_usage[t];
    if (t == 0) out[O_LOSS] = 0.0f;
  }
}

// ---------------------------------------------------------------------------
// Kernel 2: argmin replicating the reference's f32 arithmetic:
//   ze  = z.e (f64-exact accumulation, rounded to f32)
//   d   = fl( fl(zzf - 2*zef) + enf )   (all f32, elementwise)
//   idx = argmin_j d, ties -> lowest index (numpy argmin semantics)
// BM=64 rows x BN=64 codes per tile, BK=32, 256 threads, 4x4 per thread.
#define BM 64
#define BN 64
#define BK 32
#define LDP 68

__global__ __launch_bounds__(256) void vq_argmin(
    const float* __restrict__ z, const float* __restrict__ emb,
    const float* __restrict__ zzf, const float* __restrict__ enf,
    float* __restrict__ out) {
  __shared__ float As[BK][LDP];   // As[k][row]
  __shared__ float Bs[BK][LDP];   // Bs[k][code]

  const int tid = threadIdx.x;
  const int tx = tid & 15, ty = tid >> 4;
  const size_t row0 = (size_t)blockIdx.x * BM;

  float zrow2[4];
#pragma unroll
  for (int i = 0; i < 4; ++i) zrow2[i] = zzf[row0 + ty * 4 + i];

  float bv[4];
  int bj[4];
#pragma unroll
  for (int i = 0; i < 4; ++i) { bv[i] = INFINITY; bj[i] = 0; }

  for (int jt = 0; jt < NE; jt += BN) {
    double acc[4][4];
#pragma unroll
    for (int i = 0; i < 4; ++i)
#pragma unroll
      for (int j = 0; j < 4; ++j) acc[i][j] = 0.0;

    for (int k0 = 0; k0 < D_DIM; k0 += BK) {
      __syncthreads();  // protect LDS vs previous compute phase
      // stage: 64 rows x 32 k floats for A and B; 8 floats per thread each
#pragma unroll
      for (int q = 0; q < 2; ++q) {
        int u = tid + q * 256;
        int r = u >> 3;            // 0..63
        int c4 = (u & 7) * 4;      // 0..28
        float4 av = *reinterpret_cast<const float4*>(
            z + (row0 + r) * (size_t)D_DIM + k0 + c4);
        As[c4 + 0][r] = av.x; As[c4 + 1][r] = av.y;
        As[c4 + 2][r] = av.z; As[c4 + 3][r] = av.w;
        float4 ev = *reinterpret_cast<const float4*>(
            emb + (size_t)(jt + r) * D_DIM + k0 + c4);
        Bs[c4 + 0][r] = ev.x; Bs[c4 + 1][r] = ev.y;
        Bs[c4 + 2][r] = ev.z; Bs[c4 + 3][r] = ev.w;
      }
      __syncthreads();
#pragma unroll 8
      for (int k = 0; k < BK; ++k) {
        double a[4], b[4];
#pragma unroll
        for (int i = 0; i < 4; ++i) a[i] = (double)As[k][ty * 4 + i];
#pragma unroll
        for (int j = 0; j < 4; ++j) b[j] = (double)Bs[k][tx * 4 + j];
#pragma unroll
        for (int i = 0; i < 4; ++i)
#pragma unroll
          for (int j = 0; j < 4; ++j)
            acc[i][j] = fma(a[i], b[j], acc[i][j]);
      }
    }
    // epilogue: replicate reference f32 ops; ascending gj + strict < keeps
    // the lowest index on (frequent, grid-quantized) ties
#pragma unroll
    for (int j = 0; j < 4; ++j) {
      int gj = jt + tx * 4 + j;
      float ef = enf[gj];
#pragma unroll
      for (int i = 0; i < 4; ++i) {
        float zef = (float)acc[i][j];        // f32(ze), like BLAS output
        float t = zrow2[i] - 2.0f * zef;     // fl(zz - 2*ze)
        float dv = t + ef;                   // fl(... + en)
        if (dv < bv[i]) { bv[i] = dv; bj[i] = gj; }
      }
    }
  }

  // reduce across the 16 tx lanes of each ty group; tie -> lowest index
#pragma unroll
  for (int m = 1; m < 16; m <<= 1) {
#pragma unroll
    for (int i = 0; i < 4; ++i) {
      float ov = __shfl_xor(bv[i], m, 16);
      int oj = __shfl_xor(bj[i], m, 16);
      if (ov < bv[i] || (ov == bv[i] && oj < bj[i])) {
        bv[i] = ov; bj[i] = oj;
      }
    }
  }
  if (tx == 0) {
#pragma unroll
    for (int i = 0; i < 4; ++i) {
      size_t grow = row0 + (size_t)ty * 4 + i;
      int j1 = bj[i];
      out[O_IDX + grow] = (float)j1;
      out[O_AGE + j1] = 0.0f;                 // benign race: all write 0
      atomicAdd(&out[O_USAGE + j1], 1.0f);
    }
  }
}

// ---------------------------------------------------------------------------
// Kernel 3: z_q_st = z + (q - z) (mimics ref rounding), loss accumulation.
// Reads idx back from out (float-encoded, exact for values < 2^24).
__global__ __launch_bounds__(256) void vq_gather(
    const float* __restrict__ z, const float* __restrict__ emb,
    float* __restrict__ out) {
  size_t e4 = (size_t)blockIdx.x * 256 + threadIdx.x;  // float4 index
  size_t m = e4 >> 6;       // / (D/4)
  int dq = (int)(e4 & 63);
  int j = (int)out[O_IDX + m];
  float4 q = *reinterpret_cast<const float4*>(emb + (size_t)j * D_DIM + dq * 4);
  float4 zv = *reinterpret_cast<const float4*>(z + e4 * 4);
  float dx = q.x - zv.x, dy = q.y - zv.y, dz = q.z - zv.z, dw = q.w - zv.w;
  float4 o;
  o.x = zv.x + dx; o.y = zv.y + dy; o.z = zv.z + dz; o.w = zv.w + dw;
  *reinterpret_cast<float4*>(out + e4 * 4) = o;
  float ls = dx * dx + dy * dy + dz * dz + dw * dw;
#pragma unroll
  for (int off = 32; off > 0; off >>= 1) ls += __shfl_down(ls, off, 64);
  if ((threadIdx.x & 63) == 0)
    atomicAdd(out + O_LOSS, ls * (1.25f / 8388608.f));  // (1+beta)/(M*D)
}

// ---------------------------------------------------------------------------
extern "C" void kernel_launch(void* const* d_in, const int* in_sizes, int n_in,
                              void* d_out, int out_size, void* d_ws, size_t ws_size,
                              hipStream_t stream) {
  const float* z = (const float*)d_in[0];
  const float* emb = (const float*)d_in[1];
  const float* code_age = (const float*)d_in[2];
  const float* code_usage = (const float*)d_in[3];
  float* out = (float*)d_out;
  float* zzf = (float*)d_ws;
  float* enf = zzf + M_TOT;

  hipLaunchKernelGGL(vq_prep, dim3(M_TOT / 256), dim3(256), 0, stream,
                     z, emb, code_age, code_usage, out, zzf, enf);
  hipLaunchKernelGGL(vq_argmin, dim3(M_TOT / BM), dim3(256), 0, stream,
                     z, emb, zzf, enf, out);
  hipLaunchKernelGGL(vq_gather, dim3((M_TOT * (D_DIM / 4)) / 256), dim3(256), 0, stream,
                     z, emb, out);
}